// Round 8
// baseline (381.132 us; speedup 1.0000x reference)
//
#include <hip/hip_runtime.h>
#include <math.h>

#define HH 6144
#define WW 6144
constexpr int G = 50;
constexpr int NCOPY = 64;
constexpr int NG = NCOPY * G;          // 3200
constexpr int BIG = 0x0FFFFFFF;
constexpr int MINBASE = 4 * NG;        // 12800: min slots (NCOPY uints)
constexpr int CTR = MINBASE + NCOPY;   // 12864: 64 slot counters (count WAVES)
constexpr int MASTER = CTR + NCOPY;    // 12928: master counter
constexpr int C0 = MASTER + 2;         // 12930 (even -> 8B-aligned doubles)
// const tables at C0 (word offsets): dT[0,100) dRC[100,200) fva[200,250)
// fvb[250,300) dRho[300,400) dSth[400,500) dCth[500,600) dStv[600,700) dCtv[700,800)
constexpr int PXHB = C0 + 800;         // h boundaries: HH*G ints (row-major)
constexpr int PXVB = PXHB + HH * G;    // v boundaries: HH*G ints

constexpr int TPB  = 384;              // 6 waves; each wave independent
constexpr int PXT  = 16;               // px per thread
constexpr int NBLK = HH;               // 1 row per block
constexpr unsigned WPC = (HH / NCOPY) * (TPB / 64);  // waves per copy slot = 576

// ALL global atomics relaxed (agent acq/rel = L2-wide inv/wb on gfx950: r4's 2.5x
// regression). Flush->counter ordering: per-WAVE s_waitcnt vmcnt(0). No
// __syncthreads anywhere in crop_main: waves are fully decoupled (r8 theory —
// intra-block barrier coupling is the ~90us floor seen in r1..r7).
__device__ inline void ldsAddF(float* p, float v)      { __hip_atomic_fetch_add(p, v, __ATOMIC_RELAXED, __HIP_MEMORY_SCOPE_WORKGROUP); }
__device__ inline void ldsAddU(unsigned* p, unsigned v){ __hip_atomic_fetch_add(p, v, __ATOMIC_RELAXED, __HIP_MEMORY_SCOPE_WORKGROUP); }
__device__ inline void glbAddF(float* p, float v)      { __hip_atomic_fetch_add(p, v, __ATOMIC_RELAXED, __HIP_MEMORY_SCOPE_AGENT); }
__device__ inline void glbAddU(unsigned* p, unsigned v){ __hip_atomic_fetch_add(p, v, __ATOMIC_RELAXED, __HIP_MEMORY_SCOPE_AGENT); }
__device__ inline void glbMinU(unsigned* p, unsigned v){ __hip_atomic_fetch_min(p, v, __ATOMIC_RELAXED, __HIP_MEMORY_SCOPE_AGENT); }
__device__ inline unsigned glbAddCtr(unsigned* p)      { return __hip_atomic_fetch_add(p, 1u, __ATOMIC_RELAXED, __HIP_MEMORY_SCOPE_AGENT); }
__device__ inline float atomLoadF(const float* p)      { return __hip_atomic_load(p, __ATOMIC_RELAXED, __HIP_MEMORY_SCOPE_AGENT); }
__device__ inline unsigned atomLoadU(const unsigned* p){ return __hip_atomic_load(p, __ATOMIC_RELAXED, __HIP_MEMORY_SCOPE_AGENT); }

__global__ void crop_init(unsigned int* __restrict__ ws,
                          const float* __restrict__ p_rmax,
                          const float* __restrict__ p_rmin,
                          const float* __restrict__ p_thmin,
                          const float* __restrict__ p_thmax,
                          const float* __restrict__ p_tvmin,
                          const float* __restrict__ p_tvmax) {
  int i = blockIdx.x * 256 + threadIdx.x;
  if (i < MINBASE) ws[i] = 0u;
  else if (i < MINBASE + NCOPY) ws[i] = 0x7F800000u;   // +inf bits
  else if (i < C0) ws[i] = 0u;                         // counters + pad

  if (blockIdx.x == 0 && threadIdx.x < G) {
    int t = threadIdx.x;
    double u    = (double)t / (double)(G - 1);
    double rmax = (double)p_rmax[0], rmin = (double)p_rmin[0];
    double rho  = rmax + (rmin - rmax) * u;
    double th   = (double)p_thmin[0] + ((double)p_thmax[0] - (double)p_thmin[0]) * u;
    double tv   = (double)p_tvmin[0] + ((double)p_tvmax[0] - (double)p_tvmin[0]) * u;
    double cth = cos(th), sth = sin(th);
    double ctv = cos(tv), stv = sin(tv);
    double* dT   = (double*)(ws + C0);
    double* dRC  = (double*)(ws + C0 + 100);
    float*  fva  = (float*)(ws + C0 + 200);
    float*  fvb  = (float*)(ws + C0 + 250);
    double* dRho = (double*)(ws + C0 + 300);
    double* dSth = (double*)(ws + C0 + 400);
    double* dCth = (double*)(ws + C0 + 500);
    double* dStv = (double*)(ws + C0 + 600);
    double* dCtv = (double*)(ws + C0 + 700);
    dT[t]  = tan(th);
    dRC[t] = rho / cth;
    fva[t] = (float)(rho / stv);
    fvb[t] = (float)(ctv / stv);
    dRho[t] = rho; dSth[t] = sth; dCth[t] = cth; dStv[t] = stv; dCtv[t] = ctv;
  }
}

// Precompute ALL (row,g) boundary pairs once: hoists every per-block setup.
// Math bit-identical to rounds 1-7 (same f64 fma/rint clamp, same f32 search).
__global__ void crop_bounds(unsigned int* __restrict__ ws) {
  const int idx = blockIdx.x * 256 + threadIdx.x;
  if (idx >= HH * G) return;
  const int row = idx / G, g = idx - row * G;
  const int yq = min(max(row, 1), HH - 2);     // edge-effect fix == coord clamp
  const float fyq = (float)yq;

  const double* dT  = (const double*)(ws + C0);
  const double* dRC = (const double*)(ws + C0 + 100);
  const float*  fva = (const float*)(ws + C0 + 200);
  const float*  fvb = (const float*)(ws + C0 + 250);

  double xg = rint(fma(-(double)yq, dT[g], dRC[g]));  // half-even like jnp.round
  xg = fmin(fmax(xg, 0.0), (double)(WW - 1));
  int xi = (int)xg;
  ((int*)ws)[PXHB + idx] = (xi <= 1) ? 0 : (xi >= WW - 1 ? BIG : xi);

  float va = fva[g], vb = fvb[g];
  int lo = 1, hi = WW - 1;                     // EXACT f32 per-pixel condition
  while (lo < hi) {
    int m = (lo + hi) >> 1;
    float yv = rintf(fmaf(-(float)m, vb, va));
    yv = fminf(fmaxf(yv, 0.f), (float)(HH - 1));
    if (yv <= fyq) hi = m; else lo = m + 1;
  }
  ((int*)ws)[PXVB + idx] = (lo >= WW - 1) ? BIG : (lo == 1 ? 0 : lo);
}

__launch_bounds__(TPB)
__global__ void crop_main(const float* __restrict__ sp,
                          float* __restrict__ wsf,
                          float* __restrict__ out) {
  // per-WAVE private bin slices: no cross-wave traffic, no barriers
  __shared__ float    sH[TPB / 64][G + 2], sV[TPB / 64][G + 2];
  __shared__ unsigned cH[TPB / 64][G + 2], cV[TPB / 64][G + 2];
  __shared__ double valD[100];                 // last-wave finalize scratch

  const int t = threadIdx.x, y = blockIdx.x;
  const int w = t >> 6, lane = t & 63;
  const int x0 = t * PXT;

  // pixel loads first (latency overlaps everything below)
  const float4* p4 = (const float4*)(sp + (size_t)y * WW + x0);
  float4 q0 = p4[0], q1 = p4[1], q2 = p4[2], q3 = p4[3];

  // wave's boundary registers: lane l holds boundary[g=l] (l<50)
  const int* ph = (const int*)wsf + PXHB + y * G;
  const int* pv = (const int*)wsf + PXVB + y * G;
  int bh = (lane < G) ? ph[lane] : BIG;
  int bv = (lane < G) ? pv[lane] : BIG;

  // zero own slice (own-wave DS ordering; no barrier needed)
  if (lane < G + 2) { sH[w][lane] = 0.f; cH[w][lane] = 0u; sV[w][lane] = 0.f; cV[w][lane] = 0u; }

  // shuffle-based binary search: first g with bnd[g] <= x0 (nonincreasing in g).
  // 6 guarded iterations cover range 50; __shfl = bpermute, all lanes active.
  int lo = 0, hi = G;
#pragma unroll
  for (int it = 0; it < 6; ++it) {
    int m = (lo + hi) >> 1;
    int pm = __shfl(bh, m);
    if (lo < hi) { if (pm <= x0) hi = m; else lo = m + 1; }
  }
  const int lbh = lo;
  int nbp = __shfl(bh, lbh > 0 ? lbh - 1 : 0);
  const int nbh = (lbh > 0) ? nbp : BIG;
  const int kh  = min(nbh - x0, PXT);          // [1,PXT]; PXT => no crossing

  lo = 0; hi = G;
#pragma unroll
  for (int it = 0; it < 6; ++it) {
    int m = (lo + hi) >> 1;
    int pm = __shfl(bv, m);
    if (lo < hi) { if (pm <= x0) hi = m; else lo = m + 1; }
  }
  const int lbv = lo;
  nbp = __shfl(bv, lbv > 0 ? lbv - 1 : 0);
  const int nbv = (lbv > 0) ? nbp : BIG;
  const int kv  = min(nbv - x0, PXT);

  const int sh = G - lbh, sv = G - lbv;

  float px[PXT] = { q0.x,q0.y,q0.z,q0.w, q1.x,q1.y,q1.z,q1.w,
                    q2.x,q2.y,q2.z,q2.w, q3.x,q3.y,q3.z,q3.w };
  float S = 0.f, Ah = 0.f, Av = 0.f, mn = 3.4e38f;
#pragma unroll
  for (int k = 0; k < PXT; ++k) {
    float v = px[k];
    mn = fminf(mn, v);
    S += v;
    if (k + 1 == kh) Ah = S;
    if (k + 1 == kv) Av = S;
  }

  ldsAddF(&sH[w][sh], Ah); ldsAddU(&cH[w][sh], (unsigned)kh);
  if (kh < PXT) { ldsAddF(&sH[w][sh + 1], S - Ah); ldsAddU(&cH[w][sh + 1], (unsigned)(PXT - kh)); }
  ldsAddF(&sV[w][sv], Av); ldsAddU(&cV[w][sv], (unsigned)kv);
  if (kv < PXT) { ldsAddF(&sV[w][sv + 1], S - Av); ldsAddU(&cV[w][sv + 1], (unsigned)(PXT - kv)); }

  // wave min
  for (int off = 32; off; off >>= 1) mn = fminf(mn, __shfl_down(mn, off));

  // drain this wave's DS ops, then read back own slice (no barrier)
  asm volatile("s_waitcnt lgkmcnt(0)" ::: "memory");
  __builtin_amdgcn_sched_barrier(0);

  const int copy = y & (NCOPY - 1);
  unsigned int* wsw = (unsigned int*)wsf;
  const unsigned int* wsu = (const unsigned int*)wsf;
  if (lane < G) {
    float    hs = sH[w][lane], vs = sV[w][lane];
    unsigned hc = cH[w][lane], vc = cV[w][lane];
    if (hc) { glbAddF(&wsf[copy * G + lane], hs); glbAddU(&wsw[2 * NG + copy * G + lane], hc); }
    if (vc) { glbAddF(&wsf[NG + copy * G + lane], vs); glbAddU(&wsw[3 * NG + copy * G + lane], vc); }
  }
  if (lane == 0) glbMinU(&wsw[MINBASE + copy], __float_as_uint(mn));

  // this wave's flush atomics globally performed before its counter add
  asm volatile("s_waitcnt vmcnt(0)" ::: "memory");

  int last = 0;
  if (lane == 0) {
    unsigned p1 = glbAddCtr(&wsw[CTR + copy]);          // 576 waves per slot
    if (p1 == WPC - 1u) {
      unsigned p2 = glbAddCtr(&wsw[MASTER]);            // 64 slot-winners
      last = (p2 == (unsigned)(NCOPY - 1));
    }
  }
  last = __shfl(last, 0);
  if (!last) return;

  // ---- very last wave anywhere: 64-lane finalize ----
  float vmn = __uint_as_float(atomLoadU(&wsu[MINBASE + lane]));
  for (int off = 32; off; off >>= 1) vmn = fminf(vmn, __shfl_down(vmn, off));
  const double mv = (double)__shfl(vmn, 0);

  for (int p = lane; p < 100; p += 64) {
    const int fam = p >= G;
    const int g = fam ? p - G : p;
    const int sumBase = fam ? NG : 0;
    const int cntBase = (2 + fam) * NG;
    double s = 0.0; unsigned c = 0;
#pragma unroll 8
    for (int cp = 0; cp < NCOPY; ++cp) {
      s += (double)atomLoadF(&wsf[sumBase + cp * G + g]);
      c += atomLoadU(&wsu[cntBase + cp * G + g]);
    }
    valD[p] = s - mv * (double)c;              // scale cancels in the cumsum ratio
  }
  asm volatile("s_waitcnt lgkmcnt(0)" ::: "memory");
  __builtin_amdgcn_sched_barrier(0);

  if (lane == 0) {
    auto bounds = [&](int base, int& lowerI, int& upperI) {
      double tot = 0;
      for (int s = 0; s < G; ++s) tot += valD[base + s];
      double c = 0; bool found = false; int lastI = -1; lowerI = 0;
      for (int s = 0; s < G; ++s) {
        c += valD[base + s];
        double cc = c / tot;
        if (!found && cc >= 0.01) { lowerI = s; found = true; }
        if (cc <= 0.99) lastI = s;
      }
      upperI = (lastI < 0) ? (G + 1) : (lastI + 2);  // all-false reversed argmax -> 51
    };
    int lh, uh, lv, uv;
    bounds(0, lh, uh);
    bounds(G, lv, uv);

    const double* dRho = (const double*)(wsu + C0 + 300);
    const double* dSth = (const double*)(wsu + C0 + 400);
    const double* dCth = (const double*)(wsu + C0 + 500);
    const double* dStv = (const double*)(wsu + C0 + 600);
    const double* dCtv = (const double*)(wsu + C0 + 700);

    auto tn = [&](int i) { return ((G - i) % G + G) % G; };  // python a[-i]
    int ihmin = tn(lh), ihmax = tn(uh), ivmin = tn(lv), ivmax = tn(uv);

    auto inter = [&](int ih, int iv, float* o) {
      double r1 = dRho[ih], s1 = dSth[ih], c1 = dCth[ih];
      double r2 = dRho[iv], s2 = dStv[iv], c2 = dCtv[iv];
      double det = c1 * s2 - c2 * s1;
      o[0] = (float)((r1 * s2 - r2 * s1) / det);
      o[1] = (float)((r2 * c1 - r1 * c2) / det);
    };
    inter(ihmin, ivmin, out + 0);
    inter(ihmax, ivmin, out + 2);
    inter(ihmax, ivmax, out + 4);
    inter(ihmin, ivmax, out + 6);
  }
}

extern "C" void kernel_launch(void* const* d_in, const int* in_sizes, int n_in,
                              void* d_out, int out_size, void* d_ws, size_t ws_size,
                              hipStream_t stream) {
  const float* sp    = (const float*)d_in[0];
  const float* rmax  = (const float*)d_in[1];
  const float* rmin  = (const float*)d_in[2];
  const float* thmin = (const float*)d_in[3];
  const float* thmax = (const float*)d_in[4];
  const float* tvmin = (const float*)d_in[5];
  const float* tvmax = (const float*)d_in[6];
  float* wsf  = (float*)d_ws;
  float* outp = (float*)d_out;

  crop_init<<<(C0 + 255) / 256, 256, 0, stream>>>((unsigned int*)d_ws,
                                                  rmax, rmin, thmin, thmax, tvmin, tvmax);
  crop_bounds<<<(HH * G + 255) / 256, 256, 0, stream>>>((unsigned int*)d_ws);
  crop_main<<<NBLK, TPB, 0, stream>>>(sp, wsf, outp);
}